// Round 11
// baseline (75.173 us; speedup 1.0000x reference)
//
#include <hip/hip_runtime.h>

#define BB    4
#define NN    8192
#define KK    16
#define CIN   64
#define COUTC 64
#define P     16           // points per block (= MFMA M-tile)

typedef short bf16x8 __attribute__((ext_vector_type(8)));
typedef float f32x4  __attribute__((ext_vector_type(4)));
typedef float f32x2  __attribute__((ext_vector_type(2)));

__device__ __forceinline__ unsigned short f2bf_rne(float f) {
    unsigned int u = __builtin_bit_cast(unsigned int, f);
    u += 0x7fffu + ((u >> 16) & 1u);
    return (unsigned short)(u >> 16);
}

__device__ __forceinline__ unsigned int pack_bf2(float lo, float hi) {
    return (unsigned int)f2bf_rne(lo) | ((unsigned int)f2bf_rne(hi) << 16);
}

// ---- fused prep: [0,8192) inp->bf16 ; [8192,8448) Wt ; 8448 fold ----
__global__ __launch_bounds__(256) void prep_all(
    const float* __restrict__ inp, unsigned short* __restrict__ inp_bf,
    const float* __restrict__ W, unsigned short* __restrict__ Wt,
    const float* __restrict__ l1w, const float* __restrict__ l1b,
    const float* __restrict__ centers, float* __restrict__ A1)
{
    const int blk = blockIdx.x;
    const int t   = threadIdx.x;
    if (blk < 8192) {
        const int i = blk * 256 + t;                   // 2M total
        inp_bf[i] = f2bf_rne(inp[i]);
    } else if (blk < 8448) {
        const int o    = (blk - 8192) * 256 + t;       // 65536 total
        const int cout = o >> 10;
        const int kp   = o & 1023;
        const int m    = kp >> 6;
        const int cin  = kp & 63;
        Wt[o] = f2bf_rne(W[(cin * 16 + m) * 64 + cout] * (1.0f / 16.0f));
    } else if (t < 32) {
        float bb = l1b[t];
        float a0 = 0.f, a1 = 0.f, a2 = 0.f;
        for (int c = 0; c < 16; ++c) {
            const float w0 = l1w[(c     ) * 32 + t];
            const float w1 = l1w[(16 + c) * 32 + t];
            const float w2 = l1w[(32 + c) * 32 + t];
            a0 += w0; a1 += w1; a2 += w2;
            bb -= centers[c] * w0 + centers[16 + c] * w1 + centers[32 + c] * w2;
        }
        A1[0 * 32 + t] = a0; A1[1 * 32 + t] = a1; A1[2 * 32 + t] = a2; A1[3 * 32 + t] = bb;
    }
}

__global__ __launch_bounds__(256, 6) void ptconv_fused(
    const unsigned short* __restrict__ inp_bf, // [B,N,CIN] bf16 (prep)
    const float* __restrict__ points,    // [B,N,3]
    const float* __restrict__ next_pts,  // [B,N,3]
    const int*   __restrict__ indices,   // [B,N,K]
    const unsigned short* __restrict__ Wt, // [COUT][1024] bf16 (prep)
    const float* __restrict__ A1f,       // [4][32] folded layer-1 (prep, SoA)
    const float* __restrict__ bias,      // [COUT]
    const float* __restrict__ l2w, const float* __restrict__ l2b,  // [32,16],[16]
    const float* __restrict__ l3w, const float* __restrict__ l3b,  // [16,16],[16]
    float* __restrict__ out)             // [B,N,COUT]
{
    const int t    = threadIdx.x;
    const int lane = t & 63;
    const int w    = t >> 6;             // wave id 0..3
    const int pt0  = blockIdx.x * P;
    const int b    = pt0 >> 13;          // pt0 / NN

    // s_h3t[p][m][k] bf16 ; s_fb = one cin-half of f, byte = p*1024 + m*64 + cin'*2, XOR-swizzled
    __shared__ unsigned short s_h3t[P][16][16];   // 8 KB
    __shared__ unsigned short s_fb[P][512];       // 16 KB
    // total 24.6 KB -> 6 blocks/CU

    const f32x2 zero2 = {0.f, 0.f};

    // ---------------- phase 1: MLP packed f32, weights via scalar loads (round-10 verbatim) ----------------
    {
        const int p = t >> 4, k = t & 15;
        const int pt = pt0 + p;
        const int id = indices[(size_t)pt0 * KK + t];  // coalesced
        const float* pp = points + ((size_t)(b * NN + id)) * 3;
        const float* np = next_pts + (size_t)pt * 3;
        const float px = pp[0] - np[0];
        const float py = pp[1] - np[1];
        const float pz = pp[2] - np[2];
        const f32x2 px2 = {px, px}, py2 = {py, py}, pz2 = {pz, pz};

        const f32x2* A0  = (const f32x2*)(A1f);
        const f32x2* A1v = (const f32x2*)(A1f + 32);
        const f32x2* A2  = (const f32x2*)(A1f + 64);
        const f32x2* A3  = (const f32x2*)(A1f + 96);
        f32x2 h1[16];
        #pragma unroll
        for (int j = 0; j < 16; ++j) {
            f32x2 a = __builtin_elementwise_fma(pz2, A2[j], A3[j]);
            a = __builtin_elementwise_fma(py2, A1v[j], a);
            a = __builtin_elementwise_fma(px2, A0[j], a);
            h1[j] = __builtin_elementwise_max(a, zero2);
        }

        f32x2 h2[8];
        {
            const f32x2* b2p = (const f32x2*)l2b;
            #pragma unroll
            for (int j = 0; j < 8; ++j) h2[j] = b2p[j];
        }
        #pragma unroll
        for (int i = 0; i < 32; ++i) {
            const float hv = h1[i >> 1][i & 1];
            const f32x2 hvv = {hv, hv};
            const f32x2* wr = (const f32x2*)(l2w + i * 16);   // uniform -> s_load
            #pragma unroll
            for (int j = 0; j < 8; ++j)
                h2[j] = __builtin_elementwise_fma(hvv, wr[j], h2[j]);
        }
        #pragma unroll
        for (int j = 0; j < 8; ++j) h2[j] = __builtin_elementwise_max(h2[j], zero2);

        f32x2 h3v[8];
        {
            const f32x2* b3p = (const f32x2*)l3b;
            #pragma unroll
            for (int j = 0; j < 8; ++j) h3v[j] = b3p[j];
        }
        #pragma unroll
        for (int i = 0; i < 16; ++i) {
            const float hv = h2[i >> 1][i & 1];
            const f32x2 hvv = {hv, hv};
            const f32x2* wr = (const f32x2*)(l3w + i * 16);   // uniform -> s_load
            #pragma unroll
            for (int j = 0; j < 8; ++j)
                h3v[j] = __builtin_elementwise_fma(hvv, wr[j], h3v[j]);
        }
        #pragma unroll
        for (int j = 0; j < 8; ++j) {
            const f32x2 v = __builtin_elementwise_max(h3v[j], zero2);
            s_h3t[p][2 * j    ][k] = f2bf_rne(v[0]);
            s_h3t[p][2 * j + 1][k] = f2bf_rne(v[1]);
        }
    }
    __syncthreads();

    // ---------------- phase 2: f = feats @ h3 via MFMA; tiles 0,1 -> LDS, tiles 2,3 -> regs ----------------
    uint2 holdA[2][2], holdB[2][2];          // [pr][tile-2], static-indexed (unrolled)
    {
        const int arow = lane & 15;          // A-row = cin_local ; B-col = m
        const int hi   = lane >> 4;
        const int kg   = (hi & 1) * 8;       // k-group base within the 16 real k
        const unsigned short* ibase = inp_bf + (size_t)b * NN * 64;
        const int* idxg = indices + (size_t)pt0 * KK;
        const bf16x8 vzero = {0, 0, 0, 0, 0, 0, 0, 0};
        char* fbb = (char*)s_fb;

        #pragma unroll
        for (int pr = 0; pr < 2; ++pr) {
            const int pA  = w * 4 + pr * 2;
            const int pB  = pA + 1;
            const int myp = (hi < 2) ? pA : pB;

            int ids[8];
            #pragma unroll
            for (int jj = 0; jj < 8; ++jj) ids[jj] = idxg[myp * 16 + kg + jj];
            const unsigned short* rb[8];
            #pragma unroll
            for (int jj = 0; jj < 8; ++jj) rb[jj] = ibase + (size_t)ids[jj] * 64 + arow;

            const bf16x8 vfull = *(const bf16x8*)&s_h3t[myp][arow][kg];
            const bf16x8 bfA = (hi < 2) ? vfull : vzero;
            const bf16x8 bfB = (hi < 2) ? vzero : vfull;

            #pragma unroll
            for (int tile = 0; tile < 4; ++tile) {
                bf16x8 af;
                #pragma unroll
                for (int jj = 0; jj < 8; ++jj) af[jj] = (short)rb[jj][tile * 16];
                const f32x4 z4 = {0.f, 0.f, 0.f, 0.f};
                const f32x4 dA = __builtin_amdgcn_mfma_f32_16x16x32_bf16(af, bfA, z4, 0, 0, 0);
                const f32x4 dB = __builtin_amdgcn_mfma_f32_16x16x32_bf16(af, bfB, z4, 0, 0, 0);
                const uint2 vA = make_uint2(pack_bf2(dA[0], dA[1]), pack_bf2(dA[2], dA[3]));
                const uint2 vB = make_uint2(pack_bf2(dB[0], dB[1]), pack_bf2(dB[2], dB[3]));
                if (tile < 2) {
                    // even half: cin' = tile*16 + hi*4 + r  in [0,32)
                    const unsigned int baseo = (unsigned)(arow * 64 + tile * 32 + hi * 8);
                    const unsigned int offA = ((unsigned)(pA * 1024) + baseo)
                                              ^ (((unsigned)((pA & 7) ^ (arow & 7))) << 4);
                    const unsigned int offB = ((unsigned)(pB * 1024) + baseo)
                                              ^ (((unsigned)((pB & 7) ^ (arow & 7))) << 4);
                    *(uint2*)(fbb + offA) = vA;
                    *(uint2*)(fbb + offB) = vB;
                } else {
                    holdA[pr][tile - 2] = vA;
                    holdB[pr][tile - 2] = vB;
                }
            }
        }
    }
    __syncthreads();

    // ---------------- phase 3: even k-pass, swap halves, odd k-pass ----------------
    {
        const int arow = lane & 15;      // A row = point ; B col = cout_local
        const int hi   = lane >> 4;
        const unsigned short* wb = Wt + (size_t)(w * 16 + arow) * 1024 + hi * 8;
        const char* fbb = (const char*)s_fb;
        f32x4 acc = {0.f, 0.f, 0.f, 0.f};

        #pragma unroll
        for (int m = 0; m < 16; ++m) {   // even kk = 2m  (cin 0..31)
            const unsigned int xr = ((unsigned)((arow & 7) ^ (m & 7))) << 4;
            const bf16x8 av = *(const bf16x8*)(fbb +
                (((unsigned)(arow * 1024 + m * 64 + hi * 16)) ^ xr));
            const bf16x8 bv = *(const bf16x8*)(wb + m * 64);
            acc = __builtin_amdgcn_mfma_f32_16x16x32_bf16(av, bv, acc, 0, 0, 0);
        }
        __syncthreads();                 // even half fully read

        {   // write odd half (cin 32..63) from hold regs
            const int arowW = lane & 15;
            char* fbw = (char*)s_fb;
            #pragma unroll
            for (int pr = 0; pr < 2; ++pr) {
                const int pA = w * 4 + pr * 2;
                const int pB = pA + 1;
                #pragma unroll
                for (int t2 = 0; t2 < 2; ++t2) {
                    const unsigned int baseo = (unsigned)(arowW * 64 + t2 * 32 + hi * 8);
                    const unsigned int offA = ((unsigned)(pA * 1024) + baseo)
                                              ^ (((unsigned)((pA & 7) ^ (arowW & 7))) << 4);
                    const unsigned int offB = ((unsigned)(pB * 1024) + baseo)
                                              ^ (((unsigned)((pB & 7) ^ (arowW & 7))) << 4);
                    *(uint2*)(fbw + offA) = holdA[pr][t2];
                    *(uint2*)(fbw + offB) = holdB[pr][t2];
                }
            }
        }
        __syncthreads();                 // odd half visible

        #pragma unroll
        for (int m = 0; m < 16; ++m) {   // odd kk = 2m+1  (cin 32..63)
            const unsigned int xr = ((unsigned)((arow & 7) ^ (m & 7))) << 4;
            const bf16x8 av = *(const bf16x8*)(fbb +
                (((unsigned)(arow * 1024 + m * 64 + hi * 16)) ^ xr));
            const bf16x8 bv = *(const bf16x8*)(wb + m * 64 + 32);
            acc = __builtin_amdgcn_mfma_f32_16x16x32_bf16(av, bv, acc, 0, 0, 0);
        }

        const float bvs = bias[w * 16 + arow];
        #pragma unroll
        for (int r = 0; r < 4; ++r) {
            const int prow = hi * 4 + r;
            out[((size_t)(pt0 + prow)) * 64 + w * 16 + arow] = acc[r] + bvs;
        }
    }
}

extern "C" void kernel_launch(void* const* d_in, const int* in_sizes, int n_in,
                              void* d_out, int out_size, void* d_ws, size_t ws_size,
                              hipStream_t stream) {
    const float* inp      = (const float*)d_in[0];
    const float* points   = (const float*)d_in[1];
    const float* next_pts = (const float*)d_in[2];
    const int*   indices  = (const int*)  d_in[3];
    const float* weight   = (const float*)d_in[4];
    const float* bias     = (const float*)d_in[5];
    const float* centers  = (const float*)d_in[6];
    const float* l1w      = (const float*)d_in[7];
    const float* l1b      = (const float*)d_in[8];
    const float* l2w      = (const float*)d_in[9];
    const float* l2b      = (const float*)d_in[10];
    const float* l3w      = (const float*)d_in[11];
    const float* l3b      = (const float*)d_in[12];
    float* outp = (float*)d_out;

    unsigned short* Wt    = (unsigned short*)d_ws;                  // 128 KB @ 0
    float*          A1f   = (float*)((char*)d_ws + 131072);         // 512 B
    unsigned short* inpbf = (unsigned short*)((char*)d_ws + (1 << 20)); // 4 MB @ 1 MB

    prep_all<<<8449, 256, 0, stream>>>(inp, inpbf, weight, Wt,
                                       l1w, l1b, centers, A1f);

    const int grid = (BB * NN) / P;               // 2048 blocks
    ptconv_fused<<<grid, 256, 0, stream>>>(inpbf, points, next_pts, indices,
                                           Wt, A1f, bias,
                                           l2w, l2b, l3w, l3b, outp);
}

// Round 12
// 56.623 us; speedup vs baseline: 1.3276x; 1.3276x over previous
//
#include <hip/hip_runtime.h>

#define BB    4
#define NN    8192
#define KK    16
#define CIN   64
#define COUTC 64
#define P     16           // points per block (= MFMA M-tile)

typedef short bf16x8 __attribute__((ext_vector_type(8)));
typedef float f32x4  __attribute__((ext_vector_type(4)));
typedef float f32x2  __attribute__((ext_vector_type(2)));

__device__ __forceinline__ unsigned short f2bf_rne(float f) {
    unsigned int u = __builtin_bit_cast(unsigned int, f);
    u += 0x7fffu + ((u >> 16) & 1u);
    return (unsigned short)(u >> 16);
}

__device__ __forceinline__ unsigned int pack_bf2(float lo, float hi) {
    return (unsigned int)f2bf_rne(lo) | ((unsigned int)f2bf_rne(hi) << 16);
}

// ---- fused prep: [0,8192) inp->bf16 ; [8192,8448) Wt ; 8448 fold ----
__global__ __launch_bounds__(256) void prep_all(
    const float* __restrict__ inp, unsigned short* __restrict__ inp_bf,
    const float* __restrict__ W, unsigned short* __restrict__ Wt,
    const float* __restrict__ l1w, const float* __restrict__ l1b,
    const float* __restrict__ centers, float* __restrict__ A1)
{
    const int blk = blockIdx.x;
    const int t   = threadIdx.x;
    if (blk < 8192) {
        const int i = blk * 256 + t;                   // 2M total
        inp_bf[i] = f2bf_rne(inp[i]);
    } else if (blk < 8448) {
        const int o    = (blk - 8192) * 256 + t;       // 65536 total
        const int cout = o >> 10;
        const int kp   = o & 1023;
        const int m    = kp >> 6;
        const int cin  = kp & 63;
        Wt[o] = f2bf_rne(W[(cin * 16 + m) * 64 + cout] * (1.0f / 16.0f));
    } else if (t < 32) {
        float bb = l1b[t];
        float a0 = 0.f, a1 = 0.f, a2 = 0.f;
        for (int c = 0; c < 16; ++c) {
            const float w0 = l1w[(c     ) * 32 + t];
            const float w1 = l1w[(16 + c) * 32 + t];
            const float w2 = l1w[(32 + c) * 32 + t];
            a0 += w0; a1 += w1; a2 += w2;
            bb -= centers[c] * w0 + centers[16 + c] * w1 + centers[32 + c] * w2;
        }
        A1[0 * 32 + t] = a0; A1[1 * 32 + t] = a1; A1[2 * 32 + t] = a2; A1[3 * 32 + t] = bb;
    }
}

__global__ __launch_bounds__(256, 2) void ptconv_fused(
    const unsigned short* __restrict__ inp_bf, // [B,N,CIN] bf16 (prep)
    const float* __restrict__ points,    // [B,N,3]
    const float* __restrict__ next_pts,  // [B,N,3]
    const int*   __restrict__ indices,   // [B,N,K]
    const unsigned short* __restrict__ Wt, // [COUT][1024] bf16 (prep)
    const float* __restrict__ A1f,       // [4][32] folded layer-1 (prep, SoA)
    const float* __restrict__ bias,      // [COUT]
    const float* __restrict__ l2w, const float* __restrict__ l2b,  // [32,16],[16]
    const float* __restrict__ l3w, const float* __restrict__ l3b,  // [16,16],[16]
    float* __restrict__ out)             // [B,N,COUT]
{
    const int t    = threadIdx.x;
    const int lane = t & 63;
    const int w    = t >> 6;             // wave id 0..3
    const int pt0  = blockIdx.x * P;
    const int b    = pt0 >> 13;          // pt0 / NN

    // s_h3t[p][m][k] bf16 ; s_fb = one cin-half of f, byte = p*1024 + m*64 + cin'*2, XOR-swizzled
    __shared__ unsigned short s_h3t[P][16][16];   // 8 KB
    __shared__ unsigned short s_fb[P][512];       // 16 KB
    // total 24.6 KB -> 6 blocks/CU (LDS-limited; VGPR must stay <= ~85)

    const f32x2 zero2 = {0.f, 0.f};

    // ---------------- phase 1: MLP packed f32, weights via scalar loads ----------------
    {
        const int p = t >> 4, k = t & 15;
        const int pt = pt0 + p;
        const int id = indices[(size_t)pt0 * KK + t];  // coalesced
        const float* pp = points + ((size_t)(b * NN + id)) * 3;
        const float* np = next_pts + (size_t)pt * 3;
        const float px = pp[0] - np[0];
        const float py = pp[1] - np[1];
        const float pz = pp[2] - np[2];
        const f32x2 px2 = {px, px}, py2 = {py, py}, pz2 = {pz, pz};

        const f32x2* A0  = (const f32x2*)(A1f);
        const f32x2* A1v = (const f32x2*)(A1f + 32);
        const f32x2* A2  = (const f32x2*)(A1f + 64);
        const f32x2* A3  = (const f32x2*)(A1f + 96);
        f32x2 h1[16];
        #pragma unroll
        for (int j = 0; j < 16; ++j) {
            f32x2 a = __builtin_elementwise_fma(pz2, A2[j], A3[j]);
            a = __builtin_elementwise_fma(py2, A1v[j], a);
            a = __builtin_elementwise_fma(px2, A0[j], a);
            h1[j] = __builtin_elementwise_max(a, zero2);
        }

        f32x2 h2[8];
        {
            const f32x2* b2p = (const f32x2*)l2b;
            #pragma unroll
            for (int j = 0; j < 8; ++j) h2[j] = b2p[j];
        }
        #pragma unroll
        for (int i = 0; i < 32; ++i) {
            const float hv = h1[i >> 1][i & 1];
            const f32x2 hvv = {hv, hv};
            const f32x2* wr = (const f32x2*)(l2w + i * 16);   // uniform -> s_load
            #pragma unroll
            for (int j = 0; j < 8; ++j)
                h2[j] = __builtin_elementwise_fma(hvv, wr[j], h2[j]);
        }
        #pragma unroll
        for (int j = 0; j < 8; ++j) h2[j] = __builtin_elementwise_max(h2[j], zero2);

        f32x2 h3v[8];
        {
            const f32x2* b3p = (const f32x2*)l3b;
            #pragma unroll
            for (int j = 0; j < 8; ++j) h3v[j] = b3p[j];
        }
        #pragma unroll
        for (int i = 0; i < 16; ++i) {
            const float hv = h2[i >> 1][i & 1];
            const f32x2 hvv = {hv, hv};
            const f32x2* wr = (const f32x2*)(l3w + i * 16);   // uniform -> s_load
            #pragma unroll
            for (int j = 0; j < 8; ++j)
                h3v[j] = __builtin_elementwise_fma(hvv, wr[j], h3v[j]);
        }
        #pragma unroll
        for (int j = 0; j < 8; ++j) {
            const f32x2 v = __builtin_elementwise_max(h3v[j], zero2);
            s_h3t[p][2 * j    ][k] = f2bf_rne(v[0]);
            s_h3t[p][2 * j + 1][k] = f2bf_rne(v[1]);
        }
    }
    __syncthreads();

    // ---------------- phase 2: f = feats @ h3 via MFMA; tiles 0,1 -> LDS, tiles 2,3 -> regs ----------------
    uint2 holdA[2][2], holdB[2][2];          // [pr][tile-2], static-indexed (unrolled)
    {
        const int arow = lane & 15;          // A-row = cin_local ; B-col = m
        const int hi   = lane >> 4;
        const int kg   = (hi & 1) * 8;       // k-group base within the 16 real k
        const unsigned short* ibase = inp_bf + (size_t)b * NN * 64;
        const int* idxg = indices + (size_t)pt0 * KK;
        const bf16x8 vzero = {0, 0, 0, 0, 0, 0, 0, 0};
        char* fbb = (char*)s_fb;

        #pragma unroll
        for (int pr = 0; pr < 2; ++pr) {
            const int pA  = w * 4 + pr * 2;
            const int pB  = pA + 1;
            const int myp = (hi < 2) ? pA : pB;

            int ids[8];
            #pragma unroll
            for (int jj = 0; jj < 8; ++jj) ids[jj] = idxg[myp * 16 + kg + jj];
            const unsigned short* rb[8];
            #pragma unroll
            for (int jj = 0; jj < 8; ++jj) rb[jj] = ibase + (size_t)ids[jj] * 64 + arow;

            const bf16x8 vfull = *(const bf16x8*)&s_h3t[myp][arow][kg];
            const bf16x8 bfA = (hi < 2) ? vfull : vzero;
            const bf16x8 bfB = (hi < 2) ? vzero : vfull;

            #pragma unroll
            for (int tile = 0; tile < 4; ++tile) {
                bf16x8 af;
                #pragma unroll
                for (int jj = 0; jj < 8; ++jj) af[jj] = (short)rb[jj][tile * 16];
                const f32x4 z4 = {0.f, 0.f, 0.f, 0.f};
                const f32x4 dA = __builtin_amdgcn_mfma_f32_16x16x32_bf16(af, bfA, z4, 0, 0, 0);
                const f32x4 dB = __builtin_amdgcn_mfma_f32_16x16x32_bf16(af, bfB, z4, 0, 0, 0);
                const uint2 vA = make_uint2(pack_bf2(dA[0], dA[1]), pack_bf2(dA[2], dA[3]));
                const uint2 vB = make_uint2(pack_bf2(dB[0], dB[1]), pack_bf2(dB[2], dB[3]));
                if (tile < 2) {
                    // even half: cin' = tile*16 + hi*4 + r  in [0,32)
                    const unsigned int baseo = (unsigned)(arow * 64 + tile * 32 + hi * 8);
                    const unsigned int offA = ((unsigned)(pA * 1024) + baseo)
                                              ^ (((unsigned)((pA & 7) ^ (arow & 7))) << 4);
                    const unsigned int offB = ((unsigned)(pB * 1024) + baseo)
                                              ^ (((unsigned)((pB & 7) ^ (arow & 7))) << 4);
                    *(uint2*)(fbb + offA) = vA;
                    *(uint2*)(fbb + offB) = vB;
                } else {
                    holdA[pr][tile - 2] = vA;
                    holdB[pr][tile - 2] = vB;
                }
            }
        }
    }
    __syncthreads();

    // ---------------- phase 3: even k-pass, swap halves, odd k-pass ----------------
    {
        const int arow = lane & 15;      // A row = point ; B col = cout_local
        const int hi   = lane >> 4;
        const unsigned short* wb = Wt + (size_t)(w * 16 + arow) * 1024 + hi * 8;
        const char* fbb = (const char*)s_fb;
        f32x4 acc = {0.f, 0.f, 0.f, 0.f};

        #pragma unroll
        for (int m = 0; m < 16; ++m) {   // even kk = 2m  (cin 0..31)
            const unsigned int xr = ((unsigned)((arow & 7) ^ (m & 7))) << 4;
            const bf16x8 av = *(const bf16x8*)(fbb +
                (((unsigned)(arow * 1024 + m * 64 + hi * 16)) ^ xr));
            const bf16x8 bv = *(const bf16x8*)(wb + m * 64);
            acc = __builtin_amdgcn_mfma_f32_16x16x32_bf16(av, bv, acc, 0, 0, 0);
        }
        __syncthreads();                 // even half fully read

        {   // write odd half (cin 32..63) from hold regs
            char* fbw = (char*)s_fb;
            #pragma unroll
            for (int pr = 0; pr < 2; ++pr) {
                const int pA = w * 4 + pr * 2;
                const int pB = pA + 1;
                #pragma unroll
                for (int t2 = 0; t2 < 2; ++t2) {
                    const unsigned int baseo = (unsigned)(arow * 64 + t2 * 32 + hi * 8);
                    const unsigned int offA = ((unsigned)(pA * 1024) + baseo)
                                              ^ (((unsigned)((pA & 7) ^ (arow & 7))) << 4);
                    const unsigned int offB = ((unsigned)(pB * 1024) + baseo)
                                              ^ (((unsigned)((pB & 7) ^ (arow & 7))) << 4);
                    *(uint2*)(fbw + offA) = holdA[pr][t2];
                    *(uint2*)(fbw + offB) = holdB[pr][t2];
                }
            }
        }
        __syncthreads();                 // odd half visible

        #pragma unroll
        for (int m = 0; m < 16; ++m) {   // odd kk = 2m+1  (cin 32..63)
            const unsigned int xr = ((unsigned)((arow & 7) ^ (m & 7))) << 4;
            const bf16x8 av = *(const bf16x8*)(fbb +
                (((unsigned)(arow * 1024 + m * 64 + hi * 16)) ^ xr));
            const bf16x8 bv = *(const bf16x8*)(wb + m * 64 + 32);
            acc = __builtin_amdgcn_mfma_f32_16x16x32_bf16(av, bv, acc, 0, 0, 0);
        }

        const float bvs = bias[w * 16 + arow];
        #pragma unroll
        for (int r = 0; r < 4; ++r) {
            const int prow = hi * 4 + r;
            out[((size_t)(pt0 + prow)) * 64 + w * 16 + arow] = acc[r] + bvs;
        }
    }
}

extern "C" void kernel_launch(void* const* d_in, const int* in_sizes, int n_in,
                              void* d_out, int out_size, void* d_ws, size_t ws_size,
                              hipStream_t stream) {
    const float* inp      = (const float*)d_in[0];
    const float* points   = (const float*)d_in[1];
    const float* next_pts = (const float*)d_in[2];
    const int*   indices  = (const int*)  d_in[3];
    const float* weight   = (const float*)d_in[4];
    const float* bias     = (const float*)d_in[5];
    const float* centers  = (const float*)d_in[6];
    const float* l1w      = (const float*)d_in[7];
    const float* l1b      = (const float*)d_in[8];
    const float* l2w      = (const float*)d_in[9];
    const float* l2b      = (const float*)d_in[10];
    const float* l3w      = (const float*)d_in[11];
    const float* l3b      = (const float*)d_in[12];
    float* outp = (float*)d_out;

    unsigned short* Wt    = (unsigned short*)d_ws;                  // 128 KB @ 0
    float*          A1f   = (float*)((char*)d_ws + 131072);         // 512 B
    unsigned short* inpbf = (unsigned short*)((char*)d_ws + (1 << 20)); // 4 MB @ 1 MB

    prep_all<<<8449, 256, 0, stream>>>(inp, inpbf, weight, Wt,
                                       l1w, l1b, centers, A1f);

    const int grid = (BB * NN) / P;               // 2048 blocks
    ptconv_fused<<<grid, 256, 0, stream>>>(inpbf, points, next_pts, indices,
                                           Wt, A1f, bias,
                                           l2w, l2b, l3w, l3b, outp);
}